// Round 9
// baseline (2112.616 us; speedup 1.0000x reference)
//
#include <hip/hip_runtime.h>
#include <cstdint>
#include <cstddef>

#define BB   64      // batch
#define TT   256     // time steps
#define EE   300     // embed dim
#define HH   512     // hidden
#define G4H  2048    // 4*H
#define NCLS 18
#define DFF  256
#define NBLK 128     // lstm grid blocks: 128 x (16 gate rows x 64 batch)

typedef short short8 __attribute__((ext_vector_type(8)));
typedef float f32x4  __attribute__((ext_vector_type(4)));

__device__ __forceinline__ float fast_exp2(float x) { return __builtin_amdgcn_exp2f(x); }
__device__ __forceinline__ float sigmoid_f(float x) {
  return 1.0f / (1.0f + fast_exp2(x * -1.442695040888963f));
}
__device__ __forceinline__ float tanh_f(float x) {
  return 2.0f / (1.0f + fast_exp2(x * -2.885390081777927f)) - 1.0f;
}
// bf16 round-to-nearest-even split helpers
__device__ __forceinline__ unsigned bf16_rne(float x) {
  unsigned u = __float_as_uint(x);
  return (u + 0x7FFFu + ((u >> 16) & 1u)) >> 16;
}
__device__ __forceinline__ float bf16_f32(unsigned hi) { return __uint_as_float(hi << 16); }

// ---------------------------------------------------------------------------
// Kernel A: embedding gather + input projection (unchanged, passing, f32).
// ---------------------------------------------------------------------------
__global__ __launch_bounds__(256) void xproj_kernel(
    const int* __restrict__ tokens, const int* __restrict__ tags,
    const float* __restrict__ emb, const float* __restrict__ W_ih,
    const float* __restrict__ b_ih, const float* __restrict__ b_hh,
    float* __restrict__ xW, int t0)
{
  const int tid  = threadIdx.x;
  const int lane = tid & 63;
  const int w    = tid >> 6;
  const int rs   = blockIdx.x & 127;
  const int tl   = blockIdx.x >> 7;
  const int t    = t0 + tl;
  const int tag  = tags[t];
  const int row0 = rs * 16;
  const int kbeg = __builtin_amdgcn_readfirstlane(w * 76);
  const bool full = (w != 3);

  const int tok = tokens[lane * TT + t];
  const float* xrow = emb + (size_t)tok * EE + kbeg;
  float xr[76];
  #pragma unroll
  for (int i = 0; i < 18; ++i) {
    const float4 v = *reinterpret_cast<const float4*>(xrow + i * 4);
    xr[i*4+0] = v.x; xr[i*4+1] = v.y; xr[i*4+2] = v.z; xr[i*4+3] = v.w;
  }
  if (full) {
    const float4 v = *reinterpret_cast<const float4*>(xrow + 72);
    xr[72] = v.x; xr[73] = v.y; xr[74] = v.z; xr[75] = v.w;
  } else {
    xr[72] = 0.f; xr[73] = 0.f; xr[74] = 0.f; xr[75] = 0.f;
  }

  const float* Wbase = W_ih + (size_t)tag * ((size_t)G4H * EE);
  __shared__ float red[4][16][64];
  #pragma unroll
  for (int r = 0; r < 16; ++r) {
    const float* Wr = Wbase + (size_t)(row0 + r) * EE + kbeg;
    float a = 0.f;
    #pragma unroll
    for (int k = 0; k < 72; ++k) a = fmaf(Wr[k], xr[k], a);
    if (full) {
      #pragma unroll
      for (int k = 72; k < 76; ++k) a = fmaf(Wr[k], xr[k], a);
    }
    red[w][r][lane] = a;
  }
  __syncthreads();
  #pragma unroll
  for (int it = 0; it < 4; ++it) {
    const int item = tid + it * 256;
    const int r = item >> 6, b = item & 63;
    const int row = row0 + r;
    float s = red[0][r][b] + red[1][r][b] + red[2][r][b] + red[3][r][b];
    s += b_ih[tag * G4H + row] + b_hh[tag * G4H + row];
    xW[((size_t)tl * G4H + row) * BB + b] = s;
  }
}

// ---------------------------------------------------------------------------
// Kernel B: persistent LSTM recurrence via MFMA (bf16x3 split precision).
// 128 blocks; block owns 4 hidden (16 gate rows r = gate*4+jj) x 64 batch.
// 16 waves = 4 batch-tiles x 4 k-slices. Per wave per step: 12 MFMAs
// (Whi*hhi + Whi*hlo + Wlo*hhi over 4 ksteps of K=32). h stored by
// producers as bf16 hi/lo planes [b][k] (IC-coherent sc0/sc1); B-frags are
// contiguous 16B/lane global loads. W slice split->bf16 into LDS, double-
// buffered, prefetched one step ahead. LDS k-reduce (4-way), f32 xW add,
// epilogue on waves 0..3 (lane = (jj,b)), c in registers, R6-style
// distributed-flag barrier over 128 blocks.
// ---------------------------------------------------------------------------
__global__ __launch_bounds__(1024, 4) void lstm_seq_kernel(
    const int* __restrict__ tags, const float* __restrict__ W_hh,
    const float* __restrict__ xW,
    unsigned short* __restrict__ hHiA, unsigned short* __restrict__ hLoA,
    unsigned short* __restrict__ hHiB, unsigned short* __restrict__ hLoB,
    float* __restrict__ cst, float* __restrict__ hF,
    unsigned int* __restrict__ flags, int t0, int nsteps)
{
  const int tid  = threadIdx.x;
  const int lane = tid & 63;
  const int w    = tid >> 6;              // 0..15
  const int bt   = w & 3;                 // batch tile (16 cols)
  const int ksl  = w >> 2;                // k slice (128 k)
  const int j0   = blockIdx.x * 4;        // 4 hidden units per block

  __shared__ unsigned short whi[2][16][512];   // 32 KB
  __shared__ unsigned short wlo[2][16][512];   // 32 KB
  __shared__ float pl[3][4][64][4];            // 12 KB k-reduce partials
  __shared__ float gt[4][16][20];              // gates [bt][b][r(+pad)]

  // MFMA lane roles
  const int r15 = lane & 15;              // A row / B col / D col
  const int kg  = lane >> 4;              // k group (0..3)
  const int k0  = ksl * 128;
  const int b0  = bt * 16;
  const int swzr = (r15 & 7) << 4;        // A-read LDS swizzle

  // W conversion role: wave w owns block row r=w
  const int grow = (w >> 2) * HH + j0 + (w & 3);   // global gate row for r=w
  const int swzw = (w & 7) << 4;

  // reduce/epilogue roles (waves 0..3): lh = lane>>4, ll = lane&15
  const int lh = lane >> 4, ll = lane & 15;
  const int eb = b0 + ll;                 // batch element (epilogue)
  float creg = 0.f;
  float xwv0 = 0.f, xwv1 = 0.f, xwv2 = 0.f, xwv3 = 0.f;

  // ---- prologue: stage W for step 0; load c; prefetch xW row for s=0 ----
  {
    const int tag0 = tags[t0];
    const float* wp = W_hh + (size_t)tag0 * ((size_t)G4H * HH)
                    + (size_t)grow * HH + lane * 8;
    const f32x4 wa = *reinterpret_cast<const f32x4*>(wp);
    const f32x4 wb = *reinterpret_cast<const f32x4*>(wp + 4);
    float wv[8] = {wa[0], wa[1], wa[2], wa[3], wb[0], wb[1], wb[2], wb[3]};
    short8 vhi, vlo;
    #pragma unroll
    for (int i = 0; i < 8; ++i) {
      const unsigned h = bf16_rne(wv[i]);
      vhi[i] = (short)h;
      vlo[i] = (short)bf16_rne(wv[i] - bf16_f32(h));
    }
    *reinterpret_cast<short8*>((char*)&whi[0][0][0] + w * 1024 + ((lane * 16) ^ swzw)) = vhi;
    *reinterpret_cast<short8*>((char*)&wlo[0][0][0] + w * 1024 + ((lane * 16) ^ swzw)) = vlo;
    if (ksl == 0) {
      creg = cst[(size_t)(j0 + lh) * BB + eb];
      const size_t xb = ((size_t)0 * G4H + (size_t)lh * HH + j0) * BB + (b0 + ll);
      xwv0 = xW[xb]; xwv1 = xW[xb + BB]; xwv2 = xW[xb + 2*BB]; xwv3 = xW[xb + 3*BB];
    }
  }
  __syncthreads();

  for (int s = 0; s < nsteps; ++s) {
    const int t   = t0 + s;
    const int cur = s & 1, nxt = cur ^ 1;
    const unsigned short* hHiIn = (t & 1) ? hHiB : hHiA;
    const unsigned short* hLoIn = (t & 1) ? hLoB : hLoA;
    unsigned short* hHiOut = (t & 1) ? hHiA : hHiB;
    unsigned short* hLoOut = (t & 1) ? hLoA : hLoB;

    // --- issue B-frag loads (8, sc0/sc1) then next-W f32 loads (2); wait B ---
    const unsigned short* bhp = hHiIn + ((size_t)(b0 + r15) * HH + (k0 + kg * 8));
    const unsigned short* blp = hLoIn + ((size_t)(b0 + r15) * HH + (k0 + kg * 8));
    const int tagN = tags[(t + 1 < TT) ? (t + 1) : t];
    const float* wfp = W_hh + (size_t)tagN * ((size_t)G4H * HH)
                     + (size_t)grow * HH + lane * 8;
    short8 bh0, bh1, bh2, bh3, bl0, bl1, bl2, bl3;
    f32x4 wf0, wf1;
    asm volatile(
      "global_load_dwordx4 %0, %10, off sc0 sc1\n\t"
      "global_load_dwordx4 %1, %10, off offset:64 sc0 sc1\n\t"
      "global_load_dwordx4 %2, %10, off offset:128 sc0 sc1\n\t"
      "global_load_dwordx4 %3, %10, off offset:192 sc0 sc1\n\t"
      "global_load_dwordx4 %4, %11, off sc0 sc1\n\t"
      "global_load_dwordx4 %5, %11, off offset:64 sc0 sc1\n\t"
      "global_load_dwordx4 %6, %11, off offset:128 sc0 sc1\n\t"
      "global_load_dwordx4 %7, %11, off offset:192 sc0 sc1\n\t"
      "global_load_dwordx4 %8, %12, off\n\t"
      "global_load_dwordx4 %9, %12, off offset:16\n\t"
      "s_waitcnt vmcnt(2)"
      : "=&v"(bh0), "=&v"(bh1), "=&v"(bh2), "=&v"(bh3),
        "=&v"(bl0), "=&v"(bl1), "=&v"(bl2), "=&v"(bl3),
        "=&v"(wf0), "=&v"(wf1)
      : "v"(bhp), "v"(blp), "v"(wfp)
      : "memory");
    __builtin_amdgcn_sched_barrier(0);

    // --- MFMA phase: 3 split chains x 4 ksteps, A from LDS ---
    const char* wh_base = (const char*)&whi[cur][0][0];
    const char* wl_base = (const char*)&wlo[cur][0][0];
    f32x4 ahh = {0.f, 0.f, 0.f, 0.f};
    f32x4 ahl = {0.f, 0.f, 0.f, 0.f};
    f32x4 alh = {0.f, 0.f, 0.f, 0.f};
    #pragma unroll
    for (int kk = 0; kk < 4; ++kk) {
      const int kbyte = (((k0 + kk * 32 + kg * 8) * 2) ^ swzr);
      const short8 a_hi = *reinterpret_cast<const short8*>(wh_base + r15 * 1024 + kbyte);
      const short8 a_lo = *reinterpret_cast<const short8*>(wl_base + r15 * 1024 + kbyte);
      const short8 b_hi = (kk == 0) ? bh0 : (kk == 1) ? bh1 : (kk == 2) ? bh2 : bh3;
      const short8 b_lo = (kk == 0) ? bl0 : (kk == 1) ? bl1 : (kk == 2) ? bl2 : bl3;
      ahh = __builtin_amdgcn_mfma_f32_16x16x32_bf16(a_hi, b_hi, ahh, 0, 0, 0);
      ahl = __builtin_amdgcn_mfma_f32_16x16x32_bf16(a_hi, b_lo, ahl, 0, 0, 0);
      alh = __builtin_amdgcn_mfma_f32_16x16x32_bf16(a_lo, b_hi, alh, 0, 0, 0);
    }
    f32x4 Cw = ahh + ahl + alh;

    // --- convert next-step W slice into wbuf[nxt] (overlaps with reduce) ---
    asm volatile("s_waitcnt vmcnt(0)" ::: "memory");
    __builtin_amdgcn_sched_barrier(0);
    {
      float wv[8] = {wf0[0], wf0[1], wf0[2], wf0[3], wf1[0], wf1[1], wf1[2], wf1[3]};
      short8 vhi, vlo;
      #pragma unroll
      for (int i = 0; i < 8; ++i) {
        const unsigned h = bf16_rne(wv[i]);
        vhi[i] = (short)h;
        vlo[i] = (short)bf16_rne(wv[i] - bf16_f32(h));
      }
      *reinterpret_cast<short8*>((char*)&whi[nxt][0][0] + w * 1024 + ((lane * 16) ^ swzw)) = vhi;
      *reinterpret_cast<short8*>((char*)&wlo[nxt][0][0] + w * 1024 + ((lane * 16) ^ swzw)) = vlo;
    }

    // --- k-reduce: slices 1..3 park partials; slice 0 sums ---
    if (ksl) *reinterpret_cast<f32x4*>(&pl[ksl - 1][bt][lane][0]) = Cw;
    __syncthreads();                                   // sync A
    if (ksl == 0) {
      f32x4 C = Cw;
      C += *reinterpret_cast<const f32x4*>(&pl[0][bt][lane][0]);
      C += *reinterpret_cast<const f32x4*>(&pl[1][bt][lane][0]);
      C += *reinterpret_cast<const f32x4*>(&pl[2][bt][lane][0]);
      C[0] += xwv0; C[1] += xwv1; C[2] += xwv2; C[3] += xwv3;
      *reinterpret_cast<f32x4*>(&gt[bt][ll][lh * 4]) = C;   // [b][r] tile
    }
    __syncthreads();                                   // sync B
    // --- epilogue (waves 0..3): lane = (jj=lh, b=eb) ---
    if (ksl == 0) {
      const float gi = gt[bt][ll][0  + lh];
      const float gf = gt[bt][ll][4  + lh];
      const float gg = gt[bt][ll][8  + lh];
      const float go = gt[bt][ll][12 + lh];
      creg = sigmoid_f(gf) * creg + sigmoid_f(gi) * tanh_f(gg);
      const float hv = sigmoid_f(go) * tanh_f(creg);
      const unsigned hhi = bf16_rne(hv);
      const unsigned hlo = bf16_rne(hv - bf16_f32(hhi));
      unsigned short* ph = hHiOut + ((size_t)eb * HH + j0 + lh);
      unsigned short* pl2 = hLoOut + ((size_t)eb * HH + j0 + lh);
      asm volatile(
        "global_store_short %0, %1, off sc0 sc1\n\t"
        "global_store_short %2, %3, off sc0 sc1"
        :: "v"(ph), "v"(hhi), "v"(pl2), "v"(hlo) : "memory");
      if (t == TT - 1) hF[(size_t)(j0 + lh) * BB + eb] = hv;
    }
    __syncthreads();   // sync C: per-wave vmcnt drained -> h stores visible
    if (s != nsteps - 1) {
      if (tid == 0) {
        __hip_atomic_store(&flags[blockIdx.x * 16], (unsigned int)(s + 1),
                           __ATOMIC_RELAXED, __HIP_MEMORY_SCOPE_AGENT);
      }
      if (ksl == 0) {  // prefetch next xW while barrier settles
        const size_t xb = ((size_t)(s + 1) * G4H + (size_t)lh * HH + j0) * BB + (b0 + ll);
        xwv0 = xW[xb]; xwv1 = xW[xb + BB]; xwv2 = xW[xb + 2*BB]; xwv3 = xW[xb + 3*BB];
      }
      if (w == 0) {    // wave 0 polls all 128 flags (2 per lane)
        const unsigned int tgt = (unsigned int)(s + 1);
        for (;;) {
          const unsigned int f0 = __hip_atomic_load(&flags[lane * 16],
                                    __ATOMIC_RELAXED, __HIP_MEMORY_SCOPE_AGENT);
          const unsigned int f1 = __hip_atomic_load(&flags[(lane + 64) * 16],
                                    __ATOMIC_RELAXED, __HIP_MEMORY_SCOPE_AGENT);
          if (__all(f0 >= tgt && f1 >= tgt)) break;
        }
      }
      __syncthreads();                                 // sync D (release)
    }
  }
  if (ksl == 0) cst[(size_t)(j0 + lh) * BB + eb] = creg;   // chunk boundary
}

// ---------------------------------------------------------------------------
// Head 1: hid[d][b] = relu(b1[d] + sum_k W1[d][k] * h[k][b]).  Grid 32 x 1024.
// ---------------------------------------------------------------------------
__global__ __launch_bounds__(1024) void head1_kernel(
    const float* __restrict__ W1, const float* __restrict__ b1,
    const float* __restrict__ hfin, float* __restrict__ hid)
{
  const int tid  = threadIdx.x;
  const int lane = tid & 63;
  const int w    = tid >> 6;
  const int row0 = blockIdx.x * 8;
  const int kbeg = __builtin_amdgcn_readfirstlane(w * 32);
  float xr[32];
  const float* hp = hfin + (size_t)kbeg * BB + lane;
  #pragma unroll
  for (int i = 0; i < 32; ++i) xr[i] = hp[i * BB];
  __shared__ float red[16][8][64];
  #pragma unroll
  for (int r = 0; r < 8; ++r) {
    const float* Wr = W1 + (size_t)(row0 + r) * HH + kbeg;
    float a = 0.f;
    #pragma unroll
    for (int k = 0; k < 32; ++k) a = fmaf(Wr[k], xr[k], a);
    red[w][r][lane] = a;
  }
  __syncthreads();
  if (tid < 512) {
    const int r = tid >> 6, b = tid & 63;
    float s = 0.f;
    #pragma unroll
    for (int ww = 0; ww < 16; ++ww) s += red[ww][r][b];
    s += b1[row0 + r];
    hid[(size_t)(row0 + r) * BB + b] = fmaxf(s, 0.f);
  }
}

// ---------------------------------------------------------------------------
// Head 2: out[b][r] = b2[r] + sum_d W2[r][d] * hid[d][b].  1 block x 256.
// ---------------------------------------------------------------------------
__global__ __launch_bounds__(256) void head2_kernel(
    const float* __restrict__ W2, const float* __restrict__ b2,
    const float* __restrict__ hid, float* __restrict__ out)
{
  const int tid  = threadIdx.x;
  const int lane = tid & 63;
  const int w    = tid >> 6;
  const int kbeg = __builtin_amdgcn_readfirstlane(w * 64);
  float xr[64];
  const float* hp = hid + (size_t)kbeg * BB + lane;
  #pragma unroll
  for (int i = 0; i < 64; ++i) xr[i] = hp[i * BB];
  __shared__ float red[4][NCLS][64];
  #pragma unroll
  for (int r = 0; r < NCLS; ++r) {
    const float* Wr = W2 + (size_t)r * DFF + kbeg;
    float a = 0.f;
    #pragma unroll
    for (int k = 0; k < 64; ++k) a = fmaf(Wr[k], xr[k], a);
    red[w][r][lane] = a;
  }
  __syncthreads();
  for (int it = 0; it < 5; ++it) {
    const int item = tid + it * 256;
    if (item < NCLS * 64) {
      const int r = item >> 6, b = item & 63;
      float s = red[0][r][b] + red[1][r][b] + red[2][r][b] + red[3][r][b];
      out[(size_t)b * NCLS + r] = s + b2[r];
    }
  }
}

// ---------------------------------------------------------------------------
extern "C" void kernel_launch(void* const* d_in, const int* in_sizes, int n_in,
                              void* d_out, int out_size, void* d_ws, size_t ws_size,
                              hipStream_t stream)
{
  const int*   tokens = (const int*)  d_in[0];
  const int*   tags   = (const int*)  d_in[1];
  const float* emb    = (const float*)d_in[2];
  const float* W_ih   = (const float*)d_in[3];
  const float* W_hh   = (const float*)d_in[4];
  const float* b_ih   = (const float*)d_in[5];
  const float* b_hh   = (const float*)d_in[6];
  const float* W1     = (const float*)d_in[7];
  const float* b1     = (const float*)d_in[8];
  const float* W2     = (const float*)d_in[9];
  const float* b2     = (const float*)d_in[10];
  float* out = (float*)d_out;

  // ws layout: [xW chunk][h hi/lo planes x2][cst][hF][hid][flags]
  const size_t per_t = (size_t)G4H * BB * sizeof(float);   // 512 KB per timestep
  int TCH = 8;
  for (int c = 256; c >= 8; c >>= 1) {
    if ((size_t)c * per_t + (8u << 20) <= ws_size) { TCH = c; break; }
  }
  char* p = (char*)d_ws;
  float* xW = (float*)p;            p += (size_t)TCH * per_t;
  unsigned short* hHiA = (unsigned short*)p;  p += (size_t)HH * BB * 2;
  unsigned short* hLoA = (unsigned short*)p;  p += (size_t)HH * BB * 2;
  unsigned short* hHiB = (unsigned short*)p;  p += (size_t)HH * BB * 2;
  unsigned short* hLoB = (unsigned short*)p;  p += (size_t)HH * BB * 2;
  float* cst = (float*)p;           p += (size_t)HH * BB * sizeof(float);
  float* hF  = (float*)p;           p += (size_t)HH * BB * sizeof(float);
  float* hid = (float*)p;           p += (size_t)DFF * BB * sizeof(float);
  unsigned int* flags = (unsigned int*)p;     // 128*16 u32 = 8 KB

  (void)hipMemsetAsync(hHiA, 0, (size_t)HH * BB * 2, stream);  // h0 = 0
  (void)hipMemsetAsync(hLoA, 0, (size_t)HH * BB * 2, stream);
  (void)hipMemsetAsync(cst,  0, (size_t)HH * BB * sizeof(float), stream);

  for (int c0 = 0; c0 < TT; c0 += TCH) {
    xproj_kernel<<<dim3((unsigned)TCH * 128), dim3(256), 0, stream>>>(
        tokens, tags, emb, W_ih, b_ih, b_hh, xW, c0);
    (void)hipMemsetAsync(flags, 0, NBLK * 16 * sizeof(unsigned int), stream);
    {
      int t0 = c0, nsteps = TCH;
      void* args[] = { (void*)&tags, (void*)&W_hh, (void*)&xW,
                       (void*)&hHiA, (void*)&hLoA, (void*)&hHiB, (void*)&hLoB,
                       (void*)&cst, (void*)&hF, (void*)&flags,
                       (void*)&t0, (void*)&nsteps };
      hipLaunchCooperativeKernel((const void*)lstm_seq_kernel,
                                 dim3(NBLK), dim3(1024), args, 0, stream);
    }
  }
  head1_kernel<<<dim3(32), dim3(1024), 0, stream>>>(W1, b1, hF, hid);
  head2_kernel<<<dim3(1), dim3(256), 0, stream>>>(W2, b2, hid, out);
}